// Round 13
// baseline (1142.000 us; speedup 1.0000x reference)
//
#include <hip/hip_runtime.h>
#include <hip/hip_bf16.h>
#include <math.h>

typedef float f4 __attribute__((ext_vector_type(4)));
typedef _Float16 h8 __attribute__((ext_vector_type(8)));
typedef float f32x4 __attribute__((ext_vector_type(4)));

#define NB 8
#define NS 785
#define ND 128
#define NH 8
#define NDH 64
#define NDF 512
#define NL 6
#define NP 784
#define NCIN 512
#define NM (NB*NS)   // 6280

// ---------------------------------------------------------------- conv stem
__global__ __launch_bounds__(256) void conv_bn_relu_kernel(
    const float* __restrict__ x, const float* __restrict__ w,
    const float* __restrict__ gamma, const float* __restrict__ beta,
    const float* __restrict__ mean, const float* __restrict__ var,
    float* __restrict__ enc, unsigned int* __restrict__ maxv)
{
    __shared__ float xt[64][17];    // [c][p]
    __shared__ float wt[64][132];   // [c][d]
    __shared__ float red[4];
    const int b  = blockIdx.y;
    const int p0 = blockIdx.x * 16;       // 49*16 = 784 exact
    const int t  = threadIdx.x;
    const int pl = (t & 3) * 4;           // 4 pixels
    const int dl = (t >> 2) * 2;          // 2 channels
    float acc[2][4] = {};
    for (int c0 = 0; c0 < NCIN; c0 += 64) {
        __syncthreads();
        {
            int cc = t >> 2, pp = (t & 3) * 4;
            f4 v = *(const f4*)&x[(size_t)(b*NCIN + c0 + cc)*NP + p0 + pp];
            xt[cc][pp+0] = v[0]; xt[cc][pp+1] = v[1]; xt[cc][pp+2] = v[2]; xt[cc][pp+3] = v[3];
        }
        #pragma unroll
        for (int i = 0; i < 8; i++) {
            int e = t + i*256;
            int d = e >> 4, c4 = (e & 15) * 4;
            f4 v = *(const f4*)&w[(size_t)d*NCIN + c0 + c4];
            wt[c4+0][d] = v[0]; wt[c4+1][d] = v[1]; wt[c4+2][d] = v[2]; wt[c4+3][d] = v[3];
        }
        __syncthreads();
        #pragma unroll 8
        for (int cc = 0; cc < 64; cc++) {
            float w0 = wt[cc][dl], w1 = wt[cc][dl+1];
            float x0 = xt[cc][pl+0], x1 = xt[cc][pl+1], x2 = xt[cc][pl+2], x3 = xt[cc][pl+3];
            acc[0][0] += w0*x0; acc[0][1] += w0*x1; acc[0][2] += w0*x2; acc[0][3] += w0*x3;
            acc[1][0] += w1*x0; acc[1][1] += w1*x1; acc[1][2] += w1*x2; acc[1][3] += w1*x3;
        }
    }
    float lmax = 0.f;
    #pragma unroll
    for (int i = 0; i < 2; i++) {
        int d = dl + i;
        float inv = rsqrtf(var[d] + 1e-5f);
        float sc = gamma[d] * inv;
        float sh = beta[d] - mean[d] * sc;
        #pragma unroll
        for (int j = 0; j < 4; j++) {
            float vo = fmaxf(acc[i][j]*sc + sh, 0.f);
            lmax = fmaxf(lmax, vo);
            enc[(size_t)(b*NP + p0 + pl + j)*ND + d] = vo;
        }
    }
    for (int o = 1; o < 64; o <<= 1) lmax = fmaxf(lmax, __shfl_xor(lmax, o));
    if ((t & 63) == 0) red[t >> 6] = lmax;
    __syncthreads();
    if (t == 0) {
        float m2 = fmaxf(fmaxf(red[0], red[1]), fmaxf(red[2], red[3]));
        atomicMax(maxv, __float_as_uint(m2));
    }
}

// ---------------------------------------------------------------- weight f32->f16 convert
__global__ __launch_bounds__(256) void wconv_kernel(
    const float* __restrict__ w0, const float* __restrict__ w1,
    const float* __restrict__ w2, const float* __restrict__ w3,
    const float* __restrict__ w4, const float* __restrict__ w5,
    _Float16* o0, _Float16* o1, _Float16* o2,
    _Float16* o3, _Float16* o4, _Float16* o5)
{
    int t = blockIdx.x*256 + threadIdx.x;     // < 2359296 exact
    int type = t / 393216, off = t % 393216;
    const float* in; _Float16* outp;
    switch (type) {
        case 0: in = w0; outp = o0; break;
        case 1: in = w1; outp = o1; break;
        case 2: in = w2; outp = o2; break;
        case 3: in = w3; outp = o3; break;
        case 4: in = w4; outp = o4; break;
        default: in = w5; outp = o5; break;
    }
    outp[off] = (_Float16)in[off];
}

// ---------------------------------------------------------------- assemble xs/xf
__global__ void assemble_kernel(
    const float* __restrict__ encx, const float* __restrict__ ency,
    const float* __restrict__ cls, const float* __restrict__ pos,
    const float* __restrict__ maxv, float* __restrict__ xs,
    _Float16* __restrict__ xsh, _Float16* __restrict__ xfh)
{
    int i = blockIdx.x*256 + threadIdx.x;   // < 803840 exact
    int d = i & 127;
    int s = (i >> 7) % NS;
    int b = i / (NS*ND);
    float inv = 1.f / maxv[0];
    float pv = pos[s*ND + d];
    float xv, yv;
    if (s == 0) { xv = cls[d]; yv = cls[d]; }
    else {
        int idx = (b*NP + s - 1)*ND + d;
        xv = encx[idx]*inv; yv = ency[idx]*inv;
    }
    float sx = xv + pv, fx = yv + pv;
    xs[i]  = sx;
    xsh[i] = (_Float16)sx;
    xfh[i] = (_Float16)fx;
}

// ---------------------------------------------------------------- MFMA GEMM (f16 in, f32 acc)
// HW-validated frag conventions (r3/r5/r10): A/B lane row=lane&15, k-run=(lane>>4)*8
// from row-major [row][K] LDS; C/D col=lane&15, row=(lane>>4)*4+reg.
template<int ACT, int OUTH>
__global__ __launch_bounds__(256) void mfma_gemm_kernel(
    const _Float16* __restrict__ A, const _Float16* __restrict__ W,
    const float* __restrict__ bias, void* __restrict__ Cv,
    int M, int N, int K)
{
    __shared__ _Float16 At[128][40];
    __shared__ _Float16 Wt[64][40];    // W^T tile: Wt[n][k]
    const int bm = blockIdx.x * 128, bn = blockIdx.y * 64;
    const int t = threadIdx.x;
    const int lane = t & 63;
    const int wave = t >> 6;
    const int m0 = (wave >> 1) * 64;
    const int n0 = (wave & 1) * 32;
    const int lrow = lane & 15, lhi = lane >> 4;
    f32x4 acc[4][2] = {};

    for (int k0 = 0; k0 < K; k0 += 32) {
        __syncthreads();
        {
            int r = t >> 1, sg = (t & 1) * 16;
            int row = bm + r;
            h8 lo = {}, hi = {};
            if (row < M) {
                const _Float16* src = &A[(size_t)row*K + k0 + sg];
                lo = *(const h8*)&src[0];
                hi = *(const h8*)&src[8];
            }
            *(h8*)&At[r][sg]     = lo;
            *(h8*)&At[r][sg + 8] = hi;
        }
        {
            int kk = t >> 3, nseg = (t & 7) * 8;
            h8 v = *(const h8*)&W[(size_t)(k0 + kk)*N + bn + nseg];
            #pragma unroll
            for (int i = 0; i < 8; i++) Wt[nseg + i][kk] = v[i];
        }
        __syncthreads();
        h8 af[4], bf[2];
        #pragma unroll
        for (int mf = 0; mf < 4; mf++) af[mf] = *(const h8*)&At[m0 + mf*16 + lrow][lhi*8];
        #pragma unroll
        for (int nf = 0; nf < 2; nf++) bf[nf] = *(const h8*)&Wt[n0 + nf*16 + lrow][lhi*8];
        #pragma unroll
        for (int mf = 0; mf < 4; mf++)
            #pragma unroll
            for (int nf = 0; nf < 2; nf++)
                acc[mf][nf] = __builtin_amdgcn_mfma_f32_16x16x32_f16(af[mf], bf[nf], acc[mf][nf], 0, 0, 0);
    }

    #pragma unroll
    for (int nf = 0; nf < 2; nf++) {
        int col = bn + n0 + nf*16 + lrow;
        float bv = bias[col];
        #pragma unroll
        for (int mf = 0; mf < 4; mf++) {
            #pragma unroll
            for (int r = 0; r < 4; r++) {
                int row = bm + m0 + mf*16 + lhi*4 + r;
                if (row < M) {
                    float v = acc[mf][nf][r] + bv;
                    if (ACT == 1) v = 0.5f * v * (1.f + erff(v * 0.70710678118654752f));
                    if (OUTH) ((_Float16*)Cv)[(size_t)row*N + col] = (_Float16)v;
                    else      ((float*)Cv)[(size_t)row*N + col] = v;
                }
            }
        }
    }
}

// ---------------------------------------------------------------- MFMA flash attention
// Q,K,V layout [b][s][h*64+d] f16. Block: 64 q-rows, 4 waves x 16 q-rows.
// Grid (b, h, qt): same-(b,h) blocks 64 apart -> same XCD (r10: FETCH 107->9.5 MB).
// r13: r11 structure (T14/T5 reverted — measured neutral/negative) + enc mask
// hoisted to LDS once per block (removes 4 L2-latency loads from the softmax
// critical path each iteration).
__global__ __launch_bounds__(256) void attn_mfma_kernel(
    const _Float16* __restrict__ Q, const _Float16* __restrict__ K,
    const _Float16* __restrict__ V, const int* __restrict__ enc,
    _Float16* __restrict__ O)
{
    __shared__ _Float16 Ks[64][68];      // [k][d], pad 68 -> conflict-free frag reads
    __shared__ _Float16 Vt[64][68];      // [d][k]
    __shared__ _Float16 Ps[4][16][68];   // per-wave P tile [q][k]
    __shared__ float madd[832];          // mask-add per k (0 or -1e9); 13*64=832 padded
    const int b = blockIdx.x, h = blockIdx.y, qt = blockIdx.z;
    const int q0 = qt * 64;
    const int t = threadIdx.x, lane = t & 63, w = t >> 6;
    const int lrow = lane & 15, lhi = lane >> 4;

    // hoist enc mask: one coalesced pass, then only LDS broadcasts in the loop
    for (int i = t; i < 832; i += 256)
        madd[i] = (i < NS && enc[b*NS + i] == 0) ? -1e9f : 0.f;

    h8 qf[2] = {};
    {
        int qrow = q0 + w*16 + lrow;
        if (qrow < NS) {
            const _Float16* src = &Q[(size_t)(b*NS + qrow)*512 + h*64];
            #pragma unroll
            for (int ks = 0; ks < 2; ks++)
                qf[ks] = *(const h8*)&src[ks*32 + lhi*8];
        }
    }

    float m[4], l[4];
    f32x4 acc[4] = {};   // [d-frag]; col=lane&15 -> d, row regs -> q
    #pragma unroll
    for (int r = 0; r < 4; r++) { m[r] = -INFINITY; l[r] = 0.f; }

    for (int kt = 0; kt < 13; kt++) {
        int k0 = kt * 64;
        __syncthreads();   // also covers madd fill before first use
        {
            int r = t >> 2, c0 = (t & 3) * 16;
            int s = k0 + r;
            h8 lo = {}, hi = {};
            if (s < NS) {
                const _Float16* src = &K[(size_t)(b*NS + s)*512 + h*64 + c0];
                lo = *(const h8*)&src[0];
                hi = *(const h8*)&src[8];
            }
            *(h8*)&Ks[r][c0]     = lo;
            *(h8*)&Ks[r][c0 + 8] = hi;
        }
        {
            int r = t >> 2, c0 = (t & 3) * 16;
            int s = k0 + r;
            h8 a = {}, c = {};
            if (s < NS) {
                const _Float16* src = &V[(size_t)(b*NS + s)*512 + h*64 + c0];
                a = *(const h8*)&src[0];
                c = *(const h8*)&src[8];
            }
            #pragma unroll
            for (int i = 0; i < 8; i++) Vt[c0 + i][r] = a[i];
            #pragma unroll
            for (int i = 0; i < 8; i++) Vt[c0 + 8 + i][r] = c[i];
        }
        __syncthreads();

        f32x4 sc[4] = {};
        #pragma unroll
        for (int nf = 0; nf < 4; nf++)
            #pragma unroll
            for (int ks = 0; ks < 2; ks++) {
                h8 bf = *(const h8*)&Ks[nf*16 + lrow][ks*32 + lhi*8];
                sc[nf] = __builtin_amdgcn_mfma_f32_16x16x32_f16(qf[ks], bf, sc[nf], 0, 0, 0);
            }
        #pragma unroll
        for (int nf = 0; nf < 4; nf++) {
            int kk = k0 + nf*16 + lrow;          // <= 831 < 832
            float ma = madd[kk];                  // LDS broadcast across lhi groups
            bool oob = (kk >= NS);
            #pragma unroll
            for (int r = 0; r < 4; r++) {
                float v = sc[nf][r] * 0.125f + ma;
                sc[nf][r] = oob ? -INFINITY : v;
            }
        }
        float corr[4];
        #pragma unroll
        for (int r = 0; r < 4; r++) {
            float mt = fmaxf(fmaxf(sc[0][r], sc[1][r]), fmaxf(sc[2][r], sc[3][r]));
            mt = fmaxf(mt, __shfl_xor(mt, 1));
            mt = fmaxf(mt, __shfl_xor(mt, 2));
            mt = fmaxf(mt, __shfl_xor(mt, 4));
            mt = fmaxf(mt, __shfl_xor(mt, 8));
            float mn = fmaxf(m[r], mt);
            corr[r] = __expf(m[r] - mn);
            m[r] = mn;
            float ps = 0.f;
            #pragma unroll
            for (int nf = 0; nf < 4; nf++) {
                float p = __expf(sc[nf][r] - mn);
                sc[nf][r] = p;
                ps += p;
            }
            ps += __shfl_xor(ps, 1);
            ps += __shfl_xor(ps, 2);
            ps += __shfl_xor(ps, 4);
            ps += __shfl_xor(ps, 8);
            l[r] = l[r] * corr[r] + ps;
        }
        #pragma unroll
        for (int nf = 0; nf < 4; nf++)
            #pragma unroll
            for (int r = 0; r < 4; r++)
                Ps[w][lhi*4 + r][nf*16 + lrow] = (_Float16)sc[nf][r];
        // wave-local write->read fence (rule #18: waitcnt + sched_barrier)
        asm volatile("s_waitcnt lgkmcnt(0)" ::: "memory");
        __builtin_amdgcn_sched_barrier(0);
        #pragma unroll
        for (int nf = 0; nf < 4; nf++)
            #pragma unroll
            for (int r = 0; r < 4; r++) acc[nf][r] *= corr[r];
        #pragma unroll
        for (int nf = 0; nf < 4; nf++)
            #pragma unroll
            for (int ks = 0; ks < 2; ks++) {
                h8 pf = *(const h8*)&Ps[w][lrow][ks*32 + lhi*8];
                h8 vf = *(const h8*)&Vt[nf*16 + lrow][ks*32 + lhi*8];
                acc[nf] = __builtin_amdgcn_mfma_f32_16x16x32_f16(pf, vf, acc[nf], 0, 0, 0);
            }
    }
    #pragma unroll
    for (int nf = 0; nf < 4; nf++)
        #pragma unroll
        for (int r = 0; r < 4; r++) {
            int row = q0 + w*16 + lhi*4 + r;
            if (row < NS)
                O[(size_t)(b*NS + row)*512 + h*64 + nf*16 + lrow] = (_Float16)(acc[nf][r] / l[r]);
        }
}

// ---------------------------------------------------------------- residual + LN
__global__ __launch_bounds__(256) void res_ln_kernel(
    const float* X, const float* __restrict__ R,
    const float* __restrict__ g, const float* __restrict__ be,
    float* out, _Float16* __restrict__ outh)
{
    int row = blockIdx.x*4 + (threadIdx.x >> 6);
    int lane = threadIdx.x & 63;
    const float* xr = X + (size_t)row*128;
    const float* rr = R + (size_t)row*128;
    float a0 = xr[lane] + rr[lane];
    float a1 = xr[lane+64] + rr[lane+64];
    float s = a0 + a1;
    for (int o = 1; o < 64; o <<= 1) s += __shfl_xor(s, o);
    float mean = s * (1.f/128.f);
    float e0 = a0 - mean, e1 = a1 - mean;
    float vs = e0*e0 + e1*e1;
    for (int o = 1; o < 64; o <<= 1) vs += __shfl_xor(vs, o);
    float rstd = rsqrtf(vs * (1.f/128.f) + 1e-12f);
    float o0 = e0*rstd*g[lane] + be[lane];
    float o1 = e1*rstd*g[lane+64] + be[lane+64];
    out[(size_t)row*128 + lane]       = o0;
    out[(size_t)row*128 + lane + 64]  = o1;
    outh[(size_t)row*128 + lane]      = (_Float16)o0;
    outh[(size_t)row*128 + lane + 64] = (_Float16)o1;
}

// ---------------------------------------------------------------- head
__global__ __launch_bounds__(512) void head_kernel(
    const float* __restrict__ xs, const float* __restrict__ w1,
    const float* __restrict__ w2, float* __restrict__ out)
{
    __shared__ float red[8];
    int b = blockIdx.x, j = threadIdx.x;
    const float* xr = xs + (size_t)(b*NS)*128;
    float acc = 0.f;
    #pragma unroll 8
    for (int c = 0; c < 128; c++) acc += xr[c] * w1[c*512 + j];
    acc = fmaxf(acc, 0.f);
    float sv = acc * w2[j];
    for (int o = 1; o < 64; o <<= 1) sv += __shfl_xor(sv, o);
    if ((j & 63) == 0) red[j >> 6] = sv;
    __syncthreads();
    if (j == 0) {
        float r = 0.f;
        #pragma unroll
        for (int i = 0; i < 8; i++) r += red[i];
        out[b] = r;
    }
}

// ---------------------------------------------------------------- launch
extern "C" void kernel_launch(void* const* d_in, const int* in_sizes, int n_in,
                              void* d_out, int out_size, void* d_ws, size_t ws_size,
                              hipStream_t stream)
{
    const float* conv_w   = (const float*)d_in[0];
    const float* bn_gamma = (const float*)d_in[1];
    const float* bn_beta  = (const float*)d_in[2];
    const float* bn_mean  = (const float*)d_in[3];
    const float* bn_var   = (const float*)d_in[4];
    const float* pos_emb  = (const float*)d_in[5];
    const float* cls_tok  = (const float*)d_in[6];
    const float* Wq = (const float*)d_in[7];  const float* bq = (const float*)d_in[8];
    const float* Wk = (const float*)d_in[9];  const float* bk = (const float*)d_in[10];
    const float* Wv = (const float*)d_in[11]; const float* bv = (const float*)d_in[12];
    const float* Wo = (const float*)d_in[13]; const float* bo = (const float*)d_in[14];
    const float* ln1_g = (const float*)d_in[15]; const float* ln1_b = (const float*)d_in[16];
    const float* fw1 = (const float*)d_in[17]; const float* fb1 = (const float*)d_in[18];
    const float* fw2 = (const float*)d_in[19]; const float* fb2 = (const float*)d_in[20];
    const float* ln2_g = (const float*)d_in[21]; const float* ln2_b = (const float*)d_in[22];
    const float* pw1 = (const float*)d_in[23]; const float* pw2 = (const float*)d_in[24];
    const int*   enc = (const int*)d_in[25];
    const float* x   = (const float*)d_in[26];
    const float* y   = (const float*)d_in[27];
    float* out = (float*)d_out;

    // workspace (all regions 256B-aligned; ~50.5 MB total)
    char* base = (char*)d_ws;
    size_t o = 0;
    auto alloc = [&](size_t bytes) { void* p = base + o; o += bytes; return p; };
    float* maxv     = (float*)alloc(256);
    float* xs       = (float*)alloc(3215360);      // [6280][128] f32
    float* fout     = (float*)alloc(3215360);      // Wo/ffn2 out f32
    float* encx     = (float*)alloc(3211264);      // stem
    float* ency     = (float*)alloc(3211264);
    _Float16* xsh   = (_Float16*)alloc(1607680);   // f16 copies
    _Float16* xfh   = (_Float16*)alloc(1607680);
    _Float16* qh    = (_Float16*)alloc(6430720);   // [6280][512] f16
    _Float16* kh    = (_Float16*)alloc(6430720);
    _Float16* vh    = (_Float16*)alloc(6430720);
    _Float16* ctxh  = (_Float16*)alloc(6430720);
    _Float16* fmidh = (_Float16*)alloc(6430720);
    _Float16* wqh   = (_Float16*)alloc(786432);    // f16 weights, 6 layers each
    _Float16* wkh   = (_Float16*)alloc(786432);
    _Float16* wvh   = (_Float16*)alloc(786432);
    _Float16* woh   = (_Float16*)alloc(786432);
    _Float16* f1h   = (_Float16*)alloc(786432);
    _Float16* f2h   = (_Float16*)alloc(786432);

    hipMemsetAsync(d_ws, 0, 256, stream);   // zero maxval

    wconv_kernel<<<9216, 256, 0, stream>>>(Wq, Wk, Wv, Wo, fw1, fw2,
                                           wqh, wkh, wvh, woh, f1h, f2h);

    dim3 cgrid(49, NB);
    conv_bn_relu_kernel<<<cgrid, 256, 0, stream>>>(x, conv_w, bn_gamma, bn_beta,
        bn_mean, bn_var, encx, (unsigned int*)maxv);
    conv_bn_relu_kernel<<<cgrid, 256, 0, stream>>>(y, conv_w, bn_gamma, bn_beta,
        bn_mean, bn_var, ency, (unsigned int*)maxv);

    assemble_kernel<<<3140, 256, 0, stream>>>(encx, ency, cls_tok, pos_emb, maxv,
                                              xs, xsh, xfh);

    for (int i = 0; i < NL; i++) {
        const size_t wofs = (size_t)i * 128 * 512;
        mfma_gemm_kernel<0,1><<<dim3(50,8), 256, 0, stream>>>(xfh, wqh + wofs, bq + i*512, qh, NM, 512, 128);
        mfma_gemm_kernel<0,1><<<dim3(50,8), 256, 0, stream>>>(xsh, wkh + wofs, bk + i*512, kh, NM, 512, 128);
        mfma_gemm_kernel<0,1><<<dim3(50,8), 256, 0, stream>>>(xsh, wvh + wofs, bv + i*512, vh, NM, 512, 128);
        attn_mfma_kernel<<<dim3(8,8,13), 256, 0, stream>>>(qh, kh, vh, enc, ctxh);
        mfma_gemm_kernel<0,0><<<dim3(50,2), 256, 0, stream>>>(ctxh, woh + wofs, bo + i*128, fout, NM, 128, 512);
        res_ln_kernel<<<1570, 256, 0, stream>>>(xs, fout, ln1_g + i*128, ln1_b + i*128, xs, xsh);
        mfma_gemm_kernel<1,1><<<dim3(50,8), 256, 0, stream>>>(xsh, f1h + wofs, fb1 + i*512, fmidh, NM, 512, 128);
        mfma_gemm_kernel<0,0><<<dim3(50,2), 256, 0, stream>>>(fmidh, f2h + wofs, fb2 + i*128, fout, NM, 128, 512);
        res_ln_kernel<<<1570, 256, 0, stream>>>(xs, fout, ln2_g + i*128, ln2_b + i*128, xs, xsh);
    }

    head_kernel<<<8, 512, 0, stream>>>(xs, pw1, pw2, out);
}

// Round 14
// 1132.105 us; speedup vs baseline: 1.0087x; 1.0087x over previous
//
#include <hip/hip_runtime.h>
#include <hip/hip_bf16.h>
#include <math.h>

typedef float f4 __attribute__((ext_vector_type(4)));
typedef _Float16 h8 __attribute__((ext_vector_type(8)));
typedef float f32x4 __attribute__((ext_vector_type(4)));

#define NB 8
#define NS 785
#define ND 128
#define NH 8
#define NDH 64
#define NDF 512
#define NL 6
#define NP 784
#define NCIN 512
#define NM (NB*NS)   // 6280

// ---------------------------------------------------------------- conv stem
__global__ __launch_bounds__(256) void conv_bn_relu_kernel(
    const float* __restrict__ x, const float* __restrict__ w,
    const float* __restrict__ gamma, const float* __restrict__ beta,
    const float* __restrict__ mean, const float* __restrict__ var,
    float* __restrict__ enc, unsigned int* __restrict__ maxv)
{
    __shared__ float xt[64][17];    // [c][p]
    __shared__ float wt[64][132];   // [c][d]
    __shared__ float red[4];
    const int b  = blockIdx.y;
    const int p0 = blockIdx.x * 16;       // 49*16 = 784 exact
    const int t  = threadIdx.x;
    const int pl = (t & 3) * 4;           // 4 pixels
    const int dl = (t >> 2) * 2;          // 2 channels
    float acc[2][4] = {};
    for (int c0 = 0; c0 < NCIN; c0 += 64) {
        __syncthreads();
        {
            int cc = t >> 2, pp = (t & 3) * 4;
            f4 v = *(const f4*)&x[(size_t)(b*NCIN + c0 + cc)*NP + p0 + pp];
            xt[cc][pp+0] = v[0]; xt[cc][pp+1] = v[1]; xt[cc][pp+2] = v[2]; xt[cc][pp+3] = v[3];
        }
        #pragma unroll
        for (int i = 0; i < 8; i++) {
            int e = t + i*256;
            int d = e >> 4, c4 = (e & 15) * 4;
            f4 v = *(const f4*)&w[(size_t)d*NCIN + c0 + c4];
            wt[c4+0][d] = v[0]; wt[c4+1][d] = v[1]; wt[c4+2][d] = v[2]; wt[c4+3][d] = v[3];
        }
        __syncthreads();
        #pragma unroll 8
        for (int cc = 0; cc < 64; cc++) {
            float w0 = wt[cc][dl], w1 = wt[cc][dl+1];
            float x0 = xt[cc][pl+0], x1 = xt[cc][pl+1], x2 = xt[cc][pl+2], x3 = xt[cc][pl+3];
            acc[0][0] += w0*x0; acc[0][1] += w0*x1; acc[0][2] += w0*x2; acc[0][3] += w0*x3;
            acc[1][0] += w1*x0; acc[1][1] += w1*x1; acc[1][2] += w1*x2; acc[1][3] += w1*x3;
        }
    }
    float lmax = 0.f;
    #pragma unroll
    for (int i = 0; i < 2; i++) {
        int d = dl + i;
        float inv = rsqrtf(var[d] + 1e-5f);
        float sc = gamma[d] * inv;
        float sh = beta[d] - mean[d] * sc;
        #pragma unroll
        for (int j = 0; j < 4; j++) {
            float vo = fmaxf(acc[i][j]*sc + sh, 0.f);
            lmax = fmaxf(lmax, vo);
            enc[(size_t)(b*NP + p0 + pl + j)*ND + d] = vo;
        }
    }
    for (int o = 1; o < 64; o <<= 1) lmax = fmaxf(lmax, __shfl_xor(lmax, o));
    if ((t & 63) == 0) red[t >> 6] = lmax;
    __syncthreads();
    if (t == 0) {
        float m2 = fmaxf(fmaxf(red[0], red[1]), fmaxf(red[2], red[3]));
        atomicMax(maxv, __float_as_uint(m2));
    }
}

// ---------------------------------------------------------------- weight f32->f16 convert
__global__ __launch_bounds__(256) void wconv_kernel(
    const float* __restrict__ w0, const float* __restrict__ w1,
    const float* __restrict__ w2, const float* __restrict__ w3,
    const float* __restrict__ w4, const float* __restrict__ w5,
    _Float16* o0, _Float16* o1, _Float16* o2,
    _Float16* o3, _Float16* o4, _Float16* o5)
{
    int t = blockIdx.x*256 + threadIdx.x;     // < 2359296 exact
    int type = t / 393216, off = t % 393216;
    const float* in; _Float16* outp;
    switch (type) {
        case 0: in = w0; outp = o0; break;
        case 1: in = w1; outp = o1; break;
        case 2: in = w2; outp = o2; break;
        case 3: in = w3; outp = o3; break;
        case 4: in = w4; outp = o4; break;
        default: in = w5; outp = o5; break;
    }
    outp[off] = (_Float16)in[off];
}

// ---------------------------------------------------------------- assemble xs/xf
__global__ void assemble_kernel(
    const float* __restrict__ encx, const float* __restrict__ ency,
    const float* __restrict__ cls, const float* __restrict__ pos,
    const float* __restrict__ maxv, float* __restrict__ xs,
    _Float16* __restrict__ xsh, _Float16* __restrict__ xfh)
{
    int i = blockIdx.x*256 + threadIdx.x;   // < 803840 exact
    int d = i & 127;
    int s = (i >> 7) % NS;
    int b = i / (NS*ND);
    float inv = 1.f / maxv[0];
    float pv = pos[s*ND + d];
    float xv, yv;
    if (s == 0) { xv = cls[d]; yv = cls[d]; }
    else {
        int idx = (b*NP + s - 1)*ND + d;
        xv = encx[idx]*inv; yv = ency[idx]*inv;
    }
    float sx = xv + pv, fx = yv + pv;
    xs[i]  = sx;
    xsh[i] = (_Float16)sx;
    xfh[i] = (_Float16)fx;
}

// ---------------------------------------------------------------- MFMA GEMM (f16 in, f32 acc)
// HW-validated frag conventions (r3/r5/r10): A/B lane row=lane&15, k-run=(lane>>4)*8
// from row-major [row][K] LDS; C/D col=lane&15, row=(lane>>4)*4+reg.
template<int ACT, int OUTH>
__global__ __launch_bounds__(256) void mfma_gemm_kernel(
    const _Float16* __restrict__ A, const _Float16* __restrict__ W,
    const float* __restrict__ bias, void* __restrict__ Cv,
    int M, int N, int K)
{
    __shared__ _Float16 At[128][40];
    __shared__ _Float16 Wt[64][40];    // W^T tile: Wt[n][k]
    const int bm = blockIdx.x * 128, bn = blockIdx.y * 64;
    const int t = threadIdx.x;
    const int lane = t & 63;
    const int wave = t >> 6;
    const int m0 = (wave >> 1) * 64;
    const int n0 = (wave & 1) * 32;
    const int lrow = lane & 15, lhi = lane >> 4;
    f32x4 acc[4][2] = {};

    for (int k0 = 0; k0 < K; k0 += 32) {
        __syncthreads();
        {
            int r = t >> 1, sg = (t & 1) * 16;
            int row = bm + r;
            h8 lo = {}, hi = {};
            if (row < M) {
                const _Float16* src = &A[(size_t)row*K + k0 + sg];
                lo = *(const h8*)&src[0];
                hi = *(const h8*)&src[8];
            }
            *(h8*)&At[r][sg]     = lo;
            *(h8*)&At[r][sg + 8] = hi;
        }
        {
            int kk = t >> 3, nseg = (t & 7) * 8;
            h8 v = *(const h8*)&W[(size_t)(k0 + kk)*N + bn + nseg];
            #pragma unroll
            for (int i = 0; i < 8; i++) Wt[nseg + i][kk] = v[i];
        }
        __syncthreads();
        h8 af[4], bf[2];
        #pragma unroll
        for (int mf = 0; mf < 4; mf++) af[mf] = *(const h8*)&At[m0 + mf*16 + lrow][lhi*8];
        #pragma unroll
        for (int nf = 0; nf < 2; nf++) bf[nf] = *(const h8*)&Wt[n0 + nf*16 + lrow][lhi*8];
        #pragma unroll
        for (int mf = 0; mf < 4; mf++)
            #pragma unroll
            for (int nf = 0; nf < 2; nf++)
                acc[mf][nf] = __builtin_amdgcn_mfma_f32_16x16x32_f16(af[mf], bf[nf], acc[mf][nf], 0, 0, 0);
    }

    #pragma unroll
    for (int nf = 0; nf < 2; nf++) {
        int col = bn + n0 + nf*16 + lrow;
        float bv = bias[col];
        #pragma unroll
        for (int mf = 0; mf < 4; mf++) {
            #pragma unroll
            for (int r = 0; r < 4; r++) {
                int row = bm + m0 + mf*16 + lhi*4 + r;
                if (row < M) {
                    float v = acc[mf][nf][r] + bv;
                    if (ACT == 1) v = 0.5f * v * (1.f + erff(v * 0.70710678118654752f));
                    if (OUTH) ((_Float16*)Cv)[(size_t)row*N + col] = (_Float16)v;
                    else      ((float*)Cv)[(size_t)row*N + col] = v;
                }
            }
        }
    }
}

// ---------------------------------------------------------------- MFMA flash attention, split-K
// Q,K,V layout [b][s][h*64+d] f16. Block: 64 q-rows, 4 waves x 16 q-rows.
// r14: kv range split across 2 blocks (split 0: tiles 0-6, split 1: tiles 7-12)
// -> 1664 independent blocks fill the latency-idle issue slots (r11-r13 showed
// per-iteration serial chain with 70% idle). Partials (unnormalized acc, m, l)
// written to scratch; attn_combine merges. Grid (b, h, qt*2+split).
__global__ __launch_bounds__(256) void attn_mfma_kernel(
    const _Float16* __restrict__ Q, const _Float16* __restrict__ K,
    const _Float16* __restrict__ V, const int* __restrict__ enc,
    _Float16* __restrict__ Op0, _Float16* __restrict__ Op1,
    float* __restrict__ mlbuf)
{
    __shared__ _Float16 Ks[64][68];      // [k][d], pad 68 -> conflict-free frag reads
    __shared__ _Float16 Vt[64][68];      // [d][k]
    __shared__ _Float16 Ps[4][16][68];   // per-wave P tile [q][k]
    __shared__ float madd[832];          // mask-add per k (0 or -1e9)
    const int b = blockIdx.x, h = blockIdx.y;
    const int qt = blockIdx.z >> 1, split = blockIdx.z & 1;
    const int q0 = qt * 64;
    const int ktbeg = split ? 7 : 0, ktend = split ? 13 : 7;
    _Float16* Op = split ? Op1 : Op0;
    const int t = threadIdx.x, lane = t & 63, w = t >> 6;
    const int lrow = lane & 15, lhi = lane >> 4;

    for (int i = t; i < 832; i += 256)
        madd[i] = (i < NS && enc[b*NS + i] == 0) ? -1e9f : 0.f;

    h8 qf[2] = {};
    {
        int qrow = q0 + w*16 + lrow;
        if (qrow < NS) {
            const _Float16* src = &Q[(size_t)(b*NS + qrow)*512 + h*64];
            #pragma unroll
            for (int ks = 0; ks < 2; ks++)
                qf[ks] = *(const h8*)&src[ks*32 + lhi*8];
        }
    }

    float m[4], l[4];
    f32x4 acc[4] = {};   // [d-frag]; col=lane&15 -> d, row regs -> q
    #pragma unroll
    for (int r = 0; r < 4; r++) { m[r] = -INFINITY; l[r] = 0.f; }

    for (int kt = ktbeg; kt < ktend; kt++) {
        int k0 = kt * 64;
        __syncthreads();   // also covers madd fill before first use
        {
            int r = t >> 2, c0 = (t & 3) * 16;
            int s = k0 + r;
            h8 lo = {}, hi = {};
            if (s < NS) {
                const _Float16* src = &K[(size_t)(b*NS + s)*512 + h*64 + c0];
                lo = *(const h8*)&src[0];
                hi = *(const h8*)&src[8];
            }
            *(h8*)&Ks[r][c0]     = lo;
            *(h8*)&Ks[r][c0 + 8] = hi;
        }
        {
            int r = t >> 2, c0 = (t & 3) * 16;
            int s = k0 + r;
            h8 a = {}, c = {};
            if (s < NS) {
                const _Float16* src = &V[(size_t)(b*NS + s)*512 + h*64 + c0];
                a = *(const h8*)&src[0];
                c = *(const h8*)&src[8];
            }
            #pragma unroll
            for (int i = 0; i < 8; i++) Vt[c0 + i][r] = a[i];
            #pragma unroll
            for (int i = 0; i < 8; i++) Vt[c0 + 8 + i][r] = c[i];
        }
        __syncthreads();

        f32x4 sc[4] = {};
        #pragma unroll
        for (int nf = 0; nf < 4; nf++)
            #pragma unroll
            for (int ks = 0; ks < 2; ks++) {
                h8 bf = *(const h8*)&Ks[nf*16 + lrow][ks*32 + lhi*8];
                sc[nf] = __builtin_amdgcn_mfma_f32_16x16x32_f16(qf[ks], bf, sc[nf], 0, 0, 0);
            }
        #pragma unroll
        for (int nf = 0; nf < 4; nf++) {
            int kk = k0 + nf*16 + lrow;
            float ma = madd[kk];
            bool oob = (kk >= NS);
            #pragma unroll
            for (int r = 0; r < 4; r++) {
                float v = sc[nf][r] * 0.125f + ma;
                sc[nf][r] = oob ? -INFINITY : v;
            }
        }
        float corr[4];
        #pragma unroll
        for (int r = 0; r < 4; r++) {
            float mt = fmaxf(fmaxf(sc[0][r], sc[1][r]), fmaxf(sc[2][r], sc[3][r]));
            mt = fmaxf(mt, __shfl_xor(mt, 1));
            mt = fmaxf(mt, __shfl_xor(mt, 2));
            mt = fmaxf(mt, __shfl_xor(mt, 4));
            mt = fmaxf(mt, __shfl_xor(mt, 8));
            float mn = fmaxf(m[r], mt);           // first tile of each split has
            corr[r] = __expf(m[r] - mn);          // >=17 valid k -> mn finite
            m[r] = mn;
            float ps = 0.f;
            #pragma unroll
            for (int nf = 0; nf < 4; nf++) {
                float p = __expf(sc[nf][r] - mn);
                sc[nf][r] = p;
                ps += p;
            }
            ps += __shfl_xor(ps, 1);
            ps += __shfl_xor(ps, 2);
            ps += __shfl_xor(ps, 4);
            ps += __shfl_xor(ps, 8);
            l[r] = l[r] * corr[r] + ps;
        }
        #pragma unroll
        for (int nf = 0; nf < 4; nf++)
            #pragma unroll
            for (int r = 0; r < 4; r++)
                Ps[w][lhi*4 + r][nf*16 + lrow] = (_Float16)sc[nf][r];
        // wave-local write->read fence (rule #18: waitcnt + sched_barrier)
        asm volatile("s_waitcnt lgkmcnt(0)" ::: "memory");
        __builtin_amdgcn_sched_barrier(0);
        #pragma unroll
        for (int nf = 0; nf < 4; nf++)
            #pragma unroll
            for (int r = 0; r < 4; r++) acc[nf][r] *= corr[r];
        #pragma unroll
        for (int nf = 0; nf < 4; nf++)
            #pragma unroll
            for (int ks = 0; ks < 2; ks++) {
                h8 pf = *(const h8*)&Ps[w][lrow][ks*32 + lhi*8];
                h8 vf = *(const h8*)&Vt[nf*16 + lrow][ks*32 + lhi*8];
                acc[nf] = __builtin_amdgcn_mfma_f32_16x16x32_f16(pf, vf, acc[nf], 0, 0, 0);
            }
    }
    // write UNNORMALIZED partial acc + (m,l) per q-row
    #pragma unroll
    for (int nf = 0; nf < 4; nf++)
        #pragma unroll
        for (int r = 0; r < 4; r++) {
            int row = q0 + w*16 + lhi*4 + r;
            if (row < NS)
                Op[(size_t)(b*NS + row)*512 + h*64 + nf*16 + lrow] = (_Float16)acc[nf][r];
        }
    if (lrow == 0) {
        #pragma unroll
        for (int r = 0; r < 4; r++) {
            int row = q0 + w*16 + lhi*4 + r;
            if (row < NS) {
                size_t idx = (size_t)(((split*NB + b)*NH + h)*NS + row) * 2;
                mlbuf[idx]     = m[r];
                mlbuf[idx + 1] = l[r];
            }
        }
    }
}

// ---------------------------------------------------------------- split-K combine
// out[b,row,h*64+d] = (o0*w0 + o1*w1) / (l0*w0 + l1*w1), wi = exp(mi - max)
__global__ __launch_bounds__(256) void attn_combine_kernel(
    const _Float16* __restrict__ Op0, const _Float16* __restrict__ Op1,
    const float* __restrict__ mlbuf, _Float16* __restrict__ O)
{
    int i = blockIdx.x*256 + threadIdx.x;   // < 6280*512 = 3215360 exact
    int d = i & 511;
    int row = (i >> 9) % NS;
    int b = i / (NS*512);
    int h = d >> 6;
    size_t i0 = (size_t)(((0*NB + b)*NH + h)*NS + row) * 2;
    size_t i1 = (size_t)(((1*NB + b)*NH + h)*NS + row) * 2;
    float m0 = mlbuf[i0], l0 = mlbuf[i0+1];
    float m1 = mlbuf[i1], l1 = mlbuf[i1+1];
    float mm = fmaxf(m0, m1);
    float w0 = __expf(m0 - mm), w1 = __expf(m1 - mm);
    float o0 = (float)Op0[i], o1 = (float)Op1[i];
    O[i] = (_Float16)((o0*w0 + o1*w1) / (l0*w0 + l1*w1));
}

// ---------------------------------------------------------------- residual + LN
__global__ __launch_bounds__(256) void res_ln_kernel(
    const float* X, const float* __restrict__ R,
    const float* __restrict__ g, const float* __restrict__ be,
    float* out, _Float16* __restrict__ outh)
{
    int row = blockIdx.x*4 + (threadIdx.x >> 6);
    int lane = threadIdx.x & 63;
    const float* xr = X + (size_t)row*128;
    const float* rr = R + (size_t)row*128;
    float a0 = xr[lane] + rr[lane];
    float a1 = xr[lane+64] + rr[lane+64];
    float s = a0 + a1;
    for (int o = 1; o < 64; o <<= 1) s += __shfl_xor(s, o);
    float mean = s * (1.f/128.f);
    float e0 = a0 - mean, e1 = a1 - mean;
    float vs = e0*e0 + e1*e1;
    for (int o = 1; o < 64; o <<= 1) vs += __shfl_xor(vs, o);
    float rstd = rsqrtf(vs * (1.f/128.f) + 1e-12f);
    float o0 = e0*rstd*g[lane] + be[lane];
    float o1 = e1*rstd*g[lane+64] + be[lane+64];
    out[(size_t)row*128 + lane]       = o0;
    out[(size_t)row*128 + lane + 64]  = o1;
    outh[(size_t)row*128 + lane]      = (_Float16)o0;
    outh[(size_t)row*128 + lane + 64] = (_Float16)o1;
}

// ---------------------------------------------------------------- head
__global__ __launch_bounds__(512) void head_kernel(
    const float* __restrict__ xs, const float* __restrict__ w1,
    const float* __restrict__ w2, float* __restrict__ out)
{
    __shared__ float red[8];
    int b = blockIdx.x, j = threadIdx.x;
    const float* xr = xs + (size_t)(b*NS)*128;
    float acc = 0.f;
    #pragma unroll 8
    for (int c = 0; c < 128; c++) acc += xr[c] * w1[c*512 + j];
    acc = fmaxf(acc, 0.f);
    float sv = acc * w2[j];
    for (int o = 1; o < 64; o <<= 1) sv += __shfl_xor(sv, o);
    if ((j & 63) == 0) red[j >> 6] = sv;
    __syncthreads();
    if (j == 0) {
        float r = 0.f;
        #pragma unroll
        for (int i = 0; i < 8; i++) r += red[i];
        out[b] = r;
    }
}

// ---------------------------------------------------------------- launch
extern "C" void kernel_launch(void* const* d_in, const int* in_sizes, int n_in,
                              void* d_out, int out_size, void* d_ws, size_t ws_size,
                              hipStream_t stream)
{
    const float* conv_w   = (const float*)d_in[0];
    const float* bn_gamma = (const float*)d_in[1];
    const float* bn_beta  = (const float*)d_in[2];
    const float* bn_mean  = (const float*)d_in[3];
    const float* bn_var   = (const float*)d_in[4];
    const float* pos_emb  = (const float*)d_in[5];
    const float* cls_tok  = (const float*)d_in[6];
    const float* Wq = (const float*)d_in[7];  const float* bq = (const float*)d_in[8];
    const float* Wk = (const float*)d_in[9];  const float* bk = (const float*)d_in[10];
    const float* Wv = (const float*)d_in[11]; const float* bv = (const float*)d_in[12];
    const float* Wo = (const float*)d_in[13]; const float* bo = (const float*)d_in[14];
    const float* ln1_g = (const float*)d_in[15]; const float* ln1_b = (const float*)d_in[16];
    const float* fw1 = (const float*)d_in[17]; const float* fb1 = (const float*)d_in[18];
    const float* fw2 = (const float*)d_in[19]; const float* fb2 = (const float*)d_in[20];
    const float* ln2_g = (const float*)d_in[21]; const float* ln2_b = (const float*)d_in[22];
    const float* pw1 = (const float*)d_in[23]; const float* pw2 = (const float*)d_in[24];
    const int*   enc = (const int*)d_in[25];
    const float* x   = (const float*)d_in[26];
    const float* y   = (const float*)d_in[27];
    float* out = (float*)d_out;

    // workspace (all regions 256B-aligned; ~77 MB total)
    char* base = (char*)d_ws;
    size_t o = 0;
    auto alloc = [&](size_t bytes) { void* p = base + o; o += bytes; return p; };
    float* maxv     = (float*)alloc(256);
    float* xs       = (float*)alloc(3215360);      // [6280][128] f32
    float* fout     = (float*)alloc(3215360);      // Wo/ffn2 out f32
    float* encx     = (float*)alloc(3211264);      // stem
    float* ency     = (float*)alloc(3211264);
    _Float16* xsh   = (_Float16*)alloc(1607680);   // f16 copies
    _Float16* xfh   = (_Float16*)alloc(1607680);
    _Float16* qh    = (_Float16*)alloc(6430720);   // [6280][512] f16
    _Float16* kh    = (_Float16*)alloc(6430720);
    _Float16* vh    = (_Float16*)alloc(6430720);
    _Float16* ctxh  = (_Float16*)alloc(6430720);
    _Float16* fmidh = (_Float16*)alloc(6430720);
    _Float16* op0   = (_Float16*)alloc(6430720);   // split-K partials
    _Float16* op1   = (_Float16*)alloc(6430720);
    float* mlbuf    = (float*)alloc(803840);       // 2 splits * 8b * 8h * 785 * {m,l}
    _Float16* wqh   = (_Float16*)alloc(786432);    // f16 weights, 6 layers each
    _Float16* wkh   = (_Float16*)alloc(786432);
    _Float16* wvh   = (_Float16*)alloc(786432);
    _Float16* woh   = (_Float16*)alloc(786432);
    _Float16* f1h   = (_Float16*)alloc(786432);
    _Float16* f2h   = (_Float16*)alloc(786432);

    hipMemsetAsync(d_ws, 0, 256, stream);   // zero maxval

    wconv_kernel<<<9216, 256, 0, stream>>>(Wq, Wk, Wv, Wo, fw1, fw2,
                                           wqh, wkh, wvh, woh, f1h, f2h);

    dim3 cgrid(49, NB);
    conv_bn_relu_kernel<<<cgrid, 256, 0, stream>>>(x, conv_w, bn_gamma, bn_beta,
        bn_mean, bn_var, encx, (unsigned int*)maxv);
    conv_bn_relu_kernel<<<cgrid, 256, 0, stream>>>(y, conv_w, bn_gamma, bn_beta,
        bn_mean, bn_var, ency, (unsigned int*)maxv);

    assemble_kernel<<<3140, 256, 0, stream>>>(encx, ency, cls_tok, pos_emb, maxv,
                                              xs, xsh, xfh);

    for (int i = 0; i < NL; i++) {
        const size_t wofs = (size_t)i * 128 * 512;
        mfma_gemm_kernel<0,1><<<dim3(50,8), 256, 0, stream>>>(xfh, wqh + wofs, bq + i*512, qh, NM, 512, 128);
        mfma_gemm_kernel<0,1><<<dim3(50,8), 256, 0, stream>>>(xsh, wkh + wofs, bk + i*512, kh, NM, 512, 128);
        mfma_gemm_kernel<0,1><<<dim3(50,8), 256, 0, stream>>>(xsh, wvh + wofs, bv + i*512, vh, NM, 512, 128);
        attn_mfma_kernel<<<dim3(8,8,26), 256, 0, stream>>>(qh, kh, vh, enc, op0, op1, mlbuf);
        attn_combine_kernel<<<12560, 256, 0, stream>>>(op0, op1, mlbuf, ctxh);
        mfma_gemm_kernel<0,0><<<dim3(50,2), 256, 0, stream>>>(ctxh, woh + wofs, bo + i*128, fout, NM, 128, 512);
        res_ln_kernel<<<1570, 256, 0, stream>>>(xs, fout, ln1_g + i*128, ln1_b + i*128, xs, xsh);
        mfma_gemm_kernel<1,1><<<dim3(50,8), 256, 0, stream>>>(xsh, f1h + wofs, fb1 + i*512, fmidh, NM, 512, 128);
        mfma_gemm_kernel<0,0><<<dim3(50,2), 256, 0, stream>>>(fmidh, f2h + wofs, fb2 + i*128, fout, NM, 128, 512);
        res_ln_kernel<<<1570, 256, 0, stream>>>(xs, fout, ln2_g + i*128, ln2_b + i*128, xs, xsh);
    }

    head_kernel<<<8, 512, 0, stream>>>(xs, pw1, pw2, out);
}